// Round 15
// baseline (115.287 us; speedup 1.0000x reference)
//
#include <hip/hip_runtime.h>
#include <hip/hip_bf16.h>
#include <math.h>

#define Bb 4
#define Ss 4096
#define Dd 1024
#define Aa 128
#define NPAIR 272   // per batch: sum_{qb=0}^{31} ceil((qb+1)/2)

typedef __attribute__((ext_vector_type(4))) float f32x4;
typedef __attribute__((ext_vector_type(8))) short bf16x8;

static __device__ __forceinline__ unsigned short f2bf(float f) {
  union { float f; unsigned u; } v; v.f = f;
  unsigned r = v.u + 0x7fffu + ((v.u >> 16) & 1u);
  return (unsigned short)(r >> 16);
}
static __device__ __forceinline__ float bf2f(unsigned short u) {
  union { unsigned u; float f; } v; v.u = ((unsigned)u) << 16;
  return v.f;
}
static __device__ __forceinline__ unsigned int pack2bf(float lo, float hi) {
  return (unsigned int)f2bf(lo) | ((unsigned int)f2bf(hi) << 16);
}

// ---------------------------------------------------------------------------
// Kernel 0: PREP (fused).
// Blocks 0..191: Wq/Wk/Wv (fp32 [D][A]) -> fragment-major bf16 Wf:
//   Wf[((kc*24 + w*8+nj)*64 + l)*8 + j] = W_w[kc*32+(l>>4)*8+j][nj*16+(l&15)]
// Blocks 192..1215: X (fp32 [16384][1024]) -> A-fragment-major bf16 Xf:
//   Xf[((tg*32+kc)*64 + g*16 + r16)*8 + j] = X[tg*16+r16][kc*32+g*8+j]
// ---------------------------------------------------------------------------
__global__ __launch_bounds__(256) void prep_kernel(const float* __restrict__ Wq,
    const float* __restrict__ Wk, const float* __restrict__ Wv,
    const float* __restrict__ X, unsigned short* __restrict__ Wf,
    unsigned short* __restrict__ Xf) {
  const int bid = blockIdx.x;
  const int tid = threadIdx.x;
  if (bid < 192) {
    const int slot = bid * 256 + tid;                // 49152 slots
    const int l = slot & 63;
    const int rest = slot >> 6;                      // 0..767
    const int f = rest % 24;
    const int kc = rest / 24;
    const int w = f >> 3, nj = f & 7;
    const float* Wsrc = (w == 0) ? Wq : ((w == 1) ? Wk : Wv);
    const int col = nj * 16 + (l & 15);
    const int krow = kc * 32 + (l >> 4) * 8;
    unsigned short v[8];
#pragma unroll
    for (int j = 0; j < 8; ++j)
      v[j] = f2bf(Wsrc[(size_t)(krow + j) * Aa + col]);
    *reinterpret_cast<int4*>(&Wf[(size_t)slot * 8]) = *reinterpret_cast<const int4*>(v);
  } else {
    // 1024 blocks x 256 thr x 16 float4 = 4.19M float4 = full X
    const int slot2 = (bid - 192) * 256 + tid;       // 0..262143
#pragma unroll
    for (int i = 0; i < 16; ++i) {
      int p = slot2 + i * 262144;                    // float4 index
      int r = p >> 8;                                // row 0..16383
      int c4 = (p & 255) << 2;                       // col 0,4,..1020
      const float4 v = *reinterpret_cast<const float4*>(&X[(size_t)r * Dd + c4]);
      ushort4 u;
      u.x = f2bf(v.x); u.y = f2bf(v.y); u.z = f2bf(v.z); u.w = f2bf(v.w);
      int tg = r >> 4, r16 = r & 15;
      int kc = c4 >> 5, g = (c4 >> 3) & 3, j = c4 & 7;   // j = 0 or 4
      *reinterpret_cast<ushort4*>(
          &Xf[(((size_t)(tg * 32 + kc)) * 64 + g * 16 + r16) * 8 + j]) = u;
    }
  }
}

// ---------------------------------------------------------------------------
// Kernel 1: QKV projection — BARRIER-FREE, LDS-FREE (attn-kernel structure).
// Grid (256, 3) x 256 thr = 3072 independent waves (3/SIMD). Wave = 16 rows
// x 128 cols of W #blockIdx.y. All loads lane-contiguous 16B fragments:
// A from Xf (L3-resident), B from Wf (L2/L1-resident; co-resident blocks are
// same-w so B streams share L1). 16 iters of BK=64: 18 loads / 16 MFMA,
// batched 8-wide; compiler pipelines freely (no barriers to stop it).
// Q pre-scaled by (1/sqrt(A))*log2(e); V kv-slot permuted; frag-major outs.
// ---------------------------------------------------------------------------
__global__ __launch_bounds__(256) void qkv_kernel(const unsigned short* __restrict__ Xf,
    const unsigned short* __restrict__ Wf,
    unsigned short* __restrict__ Qf, unsigned short* __restrict__ Kf,
    unsigned short* __restrict__ Vf) {
  const int tid = threadIdx.x;
  const int lane = tid & 63;
  const int wid = tid >> 6;
  const int g = lane >> 4, c16 = lane & 15;
  const int mblk = blockIdx.x;               // 64-row tile, 0..255
  const int w = blockIdx.y;                  // 0=Q 1=K 2=V
  const int tg = mblk * 4 + wid;             // 16-row tile, 0..1023

  const unsigned short* Xw = Xf + (size_t)tg * 32 * 512;   // frag = 512 ushort
  f32x4 acc[8];
  const f32x4 fz = {0.f, 0.f, 0.f, 0.f};
#pragma unroll
  for (int nj = 0; nj < 8; ++nj) acc[nj] = fz;

#pragma unroll 2
  for (int t = 0; t < 16; ++t) {
    const int kc0 = 2 * t, kc1 = 2 * t + 1;
    bf16x8 a0 = *reinterpret_cast<const bf16x8*>(&Xw[((size_t)kc0 * 64 + lane) * 8]);
    bf16x8 a1 = *reinterpret_cast<const bf16x8*>(&Xw[((size_t)kc1 * 64 + lane) * 8]);
    bf16x8 b0[8];
#pragma unroll
    for (int nj = 0; nj < 8; ++nj)
      b0[nj] = *reinterpret_cast<const bf16x8*>(
          &Wf[((size_t)(kc0 * 24 + w * 8 + nj) * 64 + lane) * 8]);
#pragma unroll
    for (int nj = 0; nj < 8; ++nj)
      acc[nj] = __builtin_amdgcn_mfma_f32_16x16x32_bf16(a0, b0[nj], acc[nj], 0, 0, 0);
    bf16x8 b1[8];
#pragma unroll
    for (int nj = 0; nj < 8; ++nj)
      b1[nj] = *reinterpret_cast<const bf16x8*>(
          &Wf[((size_t)(kc1 * 24 + w * 8 + nj) * 64 + lane) * 8]);
#pragma unroll
    for (int nj = 0; nj < 8; ++nj)
      acc[nj] = __builtin_amdgcn_mfma_f32_16x16x32_bf16(a1, b1[nj], acc[nj], 0, 0, 0);
  }

  const float qscale = 0.12751744f;  // (1/sqrt(128)) * log2(e)
#pragma unroll
  for (int nj = 0; nj < 8; ++nj) {
#pragma unroll
    for (int i = 0; i < 4; ++i) {
      int grow = mblk * 64 + wid * 16 + g * 4 + i;   // global row
      int n = nj * 16 + c16;                         // col 0..127
      float val = acc[nj][i];
      if (w == 0) {
        val *= qscale;
        int tq = grow >> 4, cr = grow & 15;
        int kk = n >> 5, gq = (n >> 3) & 3, j = n & 7;
        Qf[((tq * 4 + kk) * 64 + gq * 16 + cr) * 8 + j] = f2bf(val);
      } else if (w == 1) {
        int b = grow >> 12, s = grow & 4095;
        int T16 = s >> 4, cr = s & 15;
        int kk = n >> 5, gk = (n >> 3) & 3, j = n & 7;
        Kf[(((b * 256 + T16) * 4 + kk) * 64 + gk * 16 + cr) * 8 + j] = f2bf(val);
      } else {
        int b = grow >> 12, s = grow & 4095;
        int T32 = s >> 5, v32 = s & 31;
        int sg = ((v32 & 15) << 1) | (v32 >> 4);     // permuted kv slot
        int gvn = sg >> 3, jn = sg & 7;
        int nt = n >> 4, cv = n & 15;
        Vf[(((b * 128 + T32) * 8 + nt) * 64 + gvn * 16 + cv) * 8 + jn] = f2bf(val);
      }
    }
  }
}

// ---------------------------------------------------------------------------
// Kernel 2: causal flash attention — LDS-shared K/V, 4-iteration blocks.
// (unchanged from R13/R14.)
// ---------------------------------------------------------------------------
__global__ __launch_bounds__(512) void attn_kernel(
    const unsigned short* __restrict__ Qf, const unsigned short* __restrict__ Kf,
    const unsigned short* __restrict__ Vf, unsigned int* __restrict__ PartO,
    float* __restrict__ PartL) {
  __shared__ unsigned short Kst[8192];
  __shared__ unsigned short Vst[8192];
  __shared__ unsigned int Psd[8][16][36];
  const int tid = threadIdx.x;
  const int lane = tid & 63;
  const int wid = tid >> 6;
  const int g = lane >> 4, c16 = lane & 15;

  const int bid = blockIdx.x;                    // 1088 blocks = 8 * 136
  const int xcd = bid & 7;
  const int b = xcd >> 1;
  const int p = xcd & 1;
  const int loc = (bid >> 3) * 2 + p;            // 0..271
  int qb = (int)(2.0f * sqrtf((float)loc + 1.0f));
  if (qb > 31) qb = 31;
  while (qb > 0 && ((qb + 1) * (qb + 1)) / 4 > loc) --qb;
  while (qb < 31 && ((qb + 2) * (qb + 2)) / 4 <= loc) ++qb;
  const int c = loc - ((qb + 1) * (qb + 1)) / 4;
  const int idx = b * NPAIR + loc;

  const int qbw = qb * 128 + wid * 16;
  const int tg = b * 256 + qb * 8 + wid;
  bf16x8 qf[4];
#pragma unroll
  for (int kk = 0; kk < 4; ++kk)
    qf[kk] = *reinterpret_cast<const bf16x8*>(&Qf[((size_t)(tg * 4 + kk) * 64 + lane) * 8]);

  const unsigned short* Kb0 = Kf + (size_t)b * 524288;
  const unsigned short* Vb0 = Vf + (size_t)b * 524288;

  const f32x4 fz = {0.f, 0.f, 0.f, 0.f};
  const float FM2 = 17.312340f;
  const float NEG = -1.0e30f;
  f32x4 o[8];
#pragma unroll
  for (int nt = 0; nt < 8; ++nt) o[nt] = fz;
  float lrun[4] = {0.f, 0.f, 0.f, 0.f};

#pragma unroll
  for (int it = 0; it < 4; ++it) {
    if (it) __syncthreads();
    const unsigned short* Ksrc = Kb0 + (size_t)(c * 16 + it * 4) * 2048;
    const unsigned short* Vsrc = Vb0 + (size_t)(c * 8 + it * 2) * 4096;
#pragma unroll
    for (int j = 0; j < 2; ++j) {
      int off = (tid + j * 512) * 8;
      *reinterpret_cast<int4*>(&Kst[off]) = *reinterpret_cast<const int4*>(&Ksrc[off]);
      *reinterpret_cast<int4*>(&Vst[off]) = *reinterpret_cast<const int4*>(&Vsrc[off]);
    }
    __syncthreads();

    const int kv0 = c * 256 + it * 64;
    if (kv0 <= qbw + 15) {
      f32x4 sa[4];
#pragma unroll
      for (int Tl = 0; Tl < 4; ++Tl) {
        sa[Tl] = fz;
        bf16x8 kf[4];
#pragma unroll
        for (int kk = 0; kk < 4; ++kk)
          kf[kk] = *reinterpret_cast<const bf16x8*>(&Kst[((Tl * 4 + kk) * 64 + lane) * 8]);
#pragma unroll
        for (int kk = 0; kk < 4; ++kk)
          sa[Tl] = __builtin_amdgcn_mfma_f32_16x16x32_bf16(qf[kk], kf[kk], sa[Tl], 0, 0, 0);
      }

      const bool need_mask = (kv0 + 63 > qbw);
      float pv[4][4];
#pragma unroll
      for (int i = 0; i < 4; ++i) {
        float v0 = sa[0][i], v1 = sa[1][i], v2 = sa[2][i], v3 = sa[3][i];
        if (need_mask) {
          int qrow = qbw + g * 4 + i;
          if (kv0 + c16 > qrow) v0 = NEG;
          if (kv0 + 16 + c16 > qrow) v1 = NEG;
          if (kv0 + 32 + c16 > qrow) v2 = NEG;
          if (kv0 + 48 + c16 > qrow) v3 = NEG;
        }
        float p0 = exp2f(v0 - FM2);
        float p1 = exp2f(v1 - FM2);
        float p2 = exp2f(v2 - FM2);
        float p3 = exp2f(v3 - FM2);
        lrun[i] += (p0 + p1) + (p2 + p3);
        pv[0][i] = p0; pv[1][i] = p1; pv[2][i] = p2; pv[3][i] = p3;
      }
      unsigned int* Psw = &Psd[wid][0][0];
#pragma unroll
      for (int i = 0; i < 4; ++i) {
        Psw[(4 * g + i) * 36 + c16] = pack2bf(pv[0][i], pv[1][i]);
        Psw[(4 * g + i) * 36 + 16 + c16] = pack2bf(pv[2][i], pv[3][i]);
      }
      bf16x8 pf0 = *reinterpret_cast<const bf16x8*>(&Psw[c16 * 36 + 4 * g]);
      bf16x8 pf1 = *reinterpret_cast<const bf16x8*>(&Psw[c16 * 36 + 16 + 4 * g]);
#pragma unroll
      for (int nt = 0; nt < 8; ++nt) {
        bf16x8 vf = *reinterpret_cast<const bf16x8*>(&Vst[(nt * 64 + lane) * 8]);
        o[nt] = __builtin_amdgcn_mfma_f32_16x16x32_bf16(pf0, vf, o[nt], 0, 0, 0);
      }
#pragma unroll
      for (int nt = 0; nt < 8; ++nt) {
        bf16x8 vf = *reinterpret_cast<const bf16x8*>(&Vst[((8 + nt) * 64 + lane) * 8]);
        o[nt] = __builtin_amdgcn_mfma_f32_16x16x32_bf16(pf1, vf, o[nt], 0, 0, 0);
      }
    }
  }

#pragma unroll
  for (int i = 0; i < 4; ++i) {
    float l = lrun[i];
#pragma unroll
    for (int msk = 1; msk <= 8; msk <<= 1) l += __shfl_xor(l, msk);
    lrun[i] = l;
  }
  if (c16 == 0) {
#pragma unroll
    for (int i = 0; i < 4; ++i)
      PartL[(size_t)idx * 128 + wid * 16 + g * 4 + i] = lrun[i];
  }
#pragma unroll
  for (int qd = 0; qd < 4; ++qd)
#pragma unroll
    for (int i = 0; i < 4; ++i)
      PartO[(size_t)idx * 8192 + (wid * 16 + g * 4 + i) * 64 + qd * 16 + c16] =
          pack2bf(o[2 * qd][i], o[2 * qd + 1][i]);
}

// ---------------------------------------------------------------------------
// Kernel 3: combine partials (unchanged).
// ---------------------------------------------------------------------------
__global__ __launch_bounds__(512) void combine_kernel(
    const unsigned int* __restrict__ PartO, const float* __restrict__ PartL,
    float* __restrict__ out) {
  const int bid = blockIdx.x;
  const int b = bid >> 7;
  const int sub = bid & 127;
  const int qb = sub >> 2;
  const int rq = sub & 3;
  const int tid = threadIdx.x;
  const int r = rq * 32 + (tid >> 4);
  const int dwb = (tid & 15) * 4;
  const int base = b * NPAIR + ((qb + 1) * (qb + 1)) / 4;
  const int nch = (qb + 2) >> 1;

  float accLo[4] = {0.f, 0.f, 0.f, 0.f};
  float accHi[4] = {0.f, 0.f, 0.f, 0.f};
  float l = 0.f;
  for (int c = 0; c < nch; ++c) {
    const int idx = base + c;
    l += PartL[(size_t)idx * 128 + r];
    const uint4 d = *reinterpret_cast<const uint4*>(
        &PartO[(size_t)idx * 8192 + r * 64 + dwb]);
    accLo[0] += bf2f((unsigned short)(d.x & 0xffff)); accHi[0] += bf2f((unsigned short)(d.x >> 16));
    accLo[1] += bf2f((unsigned short)(d.y & 0xffff)); accHi[1] += bf2f((unsigned short)(d.y >> 16));
    accLo[2] += bf2f((unsigned short)(d.z & 0xffff)); accHi[2] += bf2f((unsigned short)(d.z >> 16));
    accLo[3] += bf2f((unsigned short)(d.w & 0xffff)); accHi[3] += bf2f((unsigned short)(d.w >> 16));
  }
  const float inv = 1.0f / l;
  const size_t rowoff = ((size_t)b * Ss + qb * 128 + r) * Aa;
#pragma unroll
  for (int u = 0; u < 4; ++u) {
    int d = dwb + u;
    int colA = (d >> 4) * 32 + (d & 15);
    out[rowoff + colA] = rintf(accLo[u] * inv * 1e4f) * 1e-4f;
    out[rowoff + colA + 16] = rintf(accHi[u] * inv * 1e4f) * 1e-4f;
  }
}

// ---------------------------------------------------------------------------
extern "C" void kernel_launch(void* const* d_in, const int* in_sizes, int n_in,
                              void* d_out, int out_size, void* d_ws, size_t ws_size,
                              hipStream_t stream) {
  const float* X  = (const float*)d_in[0];
  const float* Wq = (const float*)d_in[1];
  const float* Wk = (const float*)d_in[2];
  const float* Wv = (const float*)d_in[3];
  float* out = (float*)d_out;

  unsigned char* ws = (unsigned char*)d_ws;
  unsigned short* Qf = (unsigned short*)(ws);                  // 4 MB fragment-major
  unsigned short* Kf = (unsigned short*)(ws + 4194304);        // 4 MB
  unsigned short* Vf = (unsigned short*)(ws + 8388608);        // 4 MB (kv-slot permuted)
  unsigned short* Wf = (unsigned short*)(ws + 12582912);       // 768 KB fragment-major
  unsigned int*  PartO = (unsigned int*)(ws + 13631488);       // 35.7 MB packed bf16
  float*         PartL = (float*)(ws + 49283072);              // 557 KB
  unsigned short* Xf = (unsigned short*)(ws + 50331648);       // 33.5 MB A-frag-major

  hipLaunchKernelGGL(prep_kernel, dim3(1216), dim3(256), 0, stream, Wq, Wk, Wv, X, Wf, Xf);
  hipLaunchKernelGGL(qkv_kernel, dim3(256, 3), dim3(256), 0, stream, Xf, Wf, Qf, Kf, Vf);
  hipLaunchKernelGGL(attn_kernel, dim3(1088), dim3(512), 0, stream, Qf, Kf, Vf, PartO, PartL);
  hipLaunchKernelGGL(combine_kernel, dim3(512), dim3(512), 0, stream, PartO, PartL, out);
}